// Round 16
// baseline (66.596 us; speedup 1.0000x reference)
//
#include <hip/hip_runtime.h>
#include <math.h>

#define NB 4
#define NN 512
#define ND 128
#define NC 10
#define NT 32                // 16-wide tiles per side
#define MREP 2               // i-tiles per wave
#define NBLK_M (NB*NT*4)     // 512 blocks: (b, Tj, q); q = octet of i-tiles

typedef short    bf16x8 __attribute__((ext_vector_type(8)));
typedef unsigned u32x4  __attribute__((ext_vector_type(4)));
typedef float    f32x4  __attribute__((ext_vector_type(4)));

// pack two f32 into two truncated bf16 (low short = a, high short = b)
static __device__ __forceinline__ unsigned pack_trunc(float a, float b) {
    unsigned ua = __builtin_bit_cast(unsigned, a);
    unsigned ub = __builtin_bit_cast(unsigned, b);
    return (ua >> 16) | (ub & 0xFFFF0000u);
}

// r11 structure (best measured: 23.7us) + in-kernel last-block finalize.
// Frag semantics (r9-r15 verified, absmax 256 vs thr 17694):
//   A-frag (g): lane l holds x[row = Ti*16 + (l&15)][d = 32g + 8*(l>>4) + e]
//   B-frag (c,g): lane l holds y_c[col = Tj*16 + (l&15)][same d-enumeration]
//   C/D: col = lane&15, row = (lane>>4)*4 + reg
__global__ __launch_bounds__(256) void w2ner_fused(
    const float* __restrict__ x, const int* __restrict__ span,
    const int* __restrict__ seqlen, const float* __restrict__ Wm,
    const float* __restrict__ bias, float* __restrict__ out,
    float* __restrict__ accum, unsigned* __restrict__ counter)
{
    __shared__ float sRed[4 * 5];
    __shared__ unsigned sLast;
    const int tid = threadIdx.x;
    const int blk = blockIdx.x;
    const int q  = blk & 3;
    const int Tj = (blk >> 2) & 31;
    const int b  = blk >> 7;
    const int wv = tid >> 6, l = tid & 63;
    const int jl = l & 15, kg = l >> 4;       // kg doubles as C/D row-group
    const int Ti0 = q * 8 + wv * MREP;
    const int j  = Tj * 16 + jl;
    const int sl = seqlen[b];
    const float* xb = x + (size_t)b * NN * ND;
    const size_t sb = (size_t)b * NN * NN;

    // span prefetch for the 8 pairs this lane owns (hides under the MFMA loop)
    int sp[MREP][4];
    #pragma unroll
    for (int m = 0; m < MREP; ++m) {
        const int ib = (Ti0 + m) * 16 + kg * 4;
        #pragma unroll
        for (int r = 0; r < 4; ++r)
            sp[m][r] = span[sb + (size_t)(ib + r) * NN + j];
    }

    // bias folded into accumulator init (MFMA C-in)
    f32x4 acc[MREP][NC];
    #pragma unroll
    for (int c = 0; c < NC; ++c) {
        const float bc = bias[c];
        #pragma unroll
        for (int m = 0; m < MREP; ++m) acc[m][c] = (f32x4){bc, bc, bc, bc};
    }

    #pragma unroll
    for (int g = 0; g < 4; ++g) {
        const int d0 = 32 * g + 8 * kg;

        // A fragments: x_i exact hi/lo split (truncation; x == hi + lo to 2^-16)
        bf16x8 ah[MREP], al[MREP];
        #pragma unroll
        for (int m = 0; m < MREP; ++m) {
            const int irow = (Ti0 + m) * 16 + jl;
            float xiv[8];
            *(float4*)&xiv[0] = *(const float4*)(xb + (size_t)irow * ND + d0);
            *(float4*)&xiv[4] = *(const float4*)(xb + (size_t)irow * ND + d0 + 4);
            u32x4 ahw, alw;
            #pragma unroll
            for (int e2 = 0; e2 < 4; ++e2) {
                const float a0 = xiv[2 * e2], a1 = xiv[2 * e2 + 1];
                const unsigned u0 = __builtin_bit_cast(unsigned, a0) & 0xFFFF0000u;
                const unsigned u1 = __builtin_bit_cast(unsigned, a1) & 0xFFFF0000u;
                ahw[e2] = (u0 >> 16) | u1;
                alw[e2] = pack_trunc(a0 - __builtin_bit_cast(float, u0),
                                     a1 - __builtin_bit_cast(float, u1));
            }
            ah[m] = __builtin_bit_cast(bf16x8, ahw);
            al[m] = __builtin_bit_cast(bf16x8, alw);
        }

        // B fragments (one per class): y = x_j * W, rounded once to bf16 (trunc)
        float xjv[8];
        *(float4*)&xjv[0] = *(const float4*)(xb + (size_t)j * ND + d0);
        *(float4*)&xjv[4] = *(const float4*)(xb + (size_t)j * ND + d0 + 4);
        u32x4 yw[NC];
        #pragma unroll
        for (int e2 = 0; e2 < 4; ++e2) {
            float wb[20];   // W rows d0+2e2, d0+2e2+1 (20 contiguous floats)
            const float4* wp = (const float4*)(Wm + (size_t)(d0 + 2 * e2) * NC);
            #pragma unroll
            for (int t5 = 0; t5 < 5; ++t5) *(float4*)&wb[4 * t5] = wp[t5];
            const float x0 = xjv[2 * e2], x1 = xjv[2 * e2 + 1];
            #pragma unroll
            for (int c = 0; c < NC; ++c)
                yw[c][e2] = pack_trunc(x0 * wb[c], x1 * wb[10 + c]);
        }

        #pragma unroll
        for (int c = 0; c < NC; ++c) {
            const bf16x8 bh = __builtin_bit_cast(bf16x8, yw[c]);
            #pragma unroll
            for (int m = 0; m < MREP; ++m) {
                acc[m][c] = __builtin_amdgcn_mfma_f32_16x16x32_bf16(ah[m], bh, acc[m][c], 0, 0, 0);
                acc[m][c] = __builtin_amdgcn_mfma_f32_16x16x32_bf16(al[m], bh, acc[m][c], 0, 0, 0);
            }
        }
    }

    // fused softmax/focal epilogue (identical to r11)
    float lsum = 0.f, accn = 0.f, tpn = 0.f, tnn = 0.f, fpn = 0.f;
    #pragma unroll
    for (int m = 0; m < MREP; ++m) {
        const int ib = (Ti0 + m) * 16 + kg * 4;
        #pragma unroll
        for (int r = 0; r < 4; ++r) {
            const int i = ib + r;
            float L[NC];
            #pragma unroll
            for (int c = 0; c < NC; ++c) L[c] = acc[m][c][r];   // bias already in
            int am = 0; float mx = L[0];
            #pragma unroll
            for (int c = 1; c < NC; ++c) { if (L[c] > mx) { mx = L[c]; am = c; } }  // first-occurrence argmax
            float e[NC]; float s = 0.f;
            #pragma unroll
            for (int c = 0; c < NC; ++c) { e[c] = __expf(L[c] - mx); s += e[c]; }
            const int spv = sp[m][r];
            float lsp = L[0], esp = e[0];
            #pragma unroll
            for (int c = 1; c < NC; ++c) {
                lsp = (spv == c) ? L[c] : lsp;
                esp = (spv == c) ? e[c] : esp;
            }
            const float inv  = __builtin_amdgcn_rcpf(s);
            const float lp   = (lsp - mx) - __logf(s);
            const float prob = esp * inv;
            const float om   = 1.f - prob;
            const float lm   = -(om * om) * lp;
            const bool v = (i < sl) && (j < sl);
            const int pred = v ? am : 0;
            out[sb + (size_t)i * NN + j] = (float)pred;
            if (v) { lsum += lm; if (pred == spv) accn += 1.f; }
            if (spv > 0) { if (pred == spv) tpn += 1.f; else tnn += 1.f; }
            else if (pred > 0 && v) fpn += 1.f;
        }
    }

    // block reduction -> per-block slot
    float vals[5] = { lsum, accn, tpn, tnn, fpn };
    #pragma unroll
    for (int k = 0; k < 5; ++k) {
        float vv = vals[k];
        for (int o = 32; o > 0; o >>= 1) vv += __shfl_down(vv, o);
        vals[k] = vv;
    }
    if (l == 0) {
        #pragma unroll
        for (int k = 0; k < 5; ++k) sRed[wv * 5 + k] = vals[k];
    }
    __syncthreads();
    if (tid < 5) {
        accum[(size_t)blk * 5 + tid] =
            sRed[tid] + sRed[5 + tid] + sRed[10 + tid] + sRed[15 + tid];
    }

    // ---- last-block finalize (replaces the second dispatch) ----
    __threadfence();                       // slots visible device-wide
    if (tid == 0) sLast = (atomicAdd(counter, 1u) == NBLK_M - 1u) ? 1u : 0u;
    __syncthreads();
    if (sLast) {
        __threadfence();                   // acquire: see all blocks' slots
        float part[5] = {0.f, 0.f, 0.f, 0.f, 0.f};
        for (int r2 = tid; r2 < NBLK_M; r2 += 256) {
            #pragma unroll
            for (int k = 0; k < 5; ++k) part[k] += accum[(size_t)r2 * 5 + k];
        }
        #pragma unroll
        for (int k = 0; k < 5; ++k) {
            float vv = part[k];
            for (int o = 32; o > 0; o >>= 1) vv += __shfl_down(vv, o);
            part[k] = vv;
        }
        __syncthreads();                   // sRed reuse barrier
        if (l == 0) {
            #pragma unroll
            for (int k = 0; k < 5; ++k) sRed[wv * 5 + k] = part[k];
        }
        __syncthreads();
        if (tid == 0) {
            float t[5];
            #pragma unroll
            for (int k = 0; k < 5; ++k)
                t[k] = sRed[k] + sRed[5 + k] + sRed[10 + k] + sRed[15 + k];
            float s2 = 0.f;
            for (int k = 0; k < NB; ++k) { float s = (float)seqlen[k]; s2 += s * s; }
            const size_t base = (size_t)NB * NN * NN;
            out[base + 0] = t[2];          // tp
            out[base + 1] = t[3];          // tn
            out[base + 2] = t[4];          // fp
            out[base + 3] = t[0] / s2;     // loss
            out[base + 4] = t[1] / s2;     // accuracy
        }
    }
}

extern "C" void kernel_launch(void* const* d_in, const int* in_sizes, int n_in,
                              void* d_out, int out_size, void* d_ws, size_t ws_size,
                              hipStream_t stream) {
    const float* x      = (const float*)d_in[0];
    const int*   span   = (const int*)d_in[1];
    const int*   seqlen = (const int*)d_in[2];
    const float* Wm     = (const float*)d_in[3];
    const float* bias   = (const float*)d_in[4];
    float* out   = (float*)d_out;

    char* ws = (char*)d_ws;
    float*    accum   = (float*)ws;                          // 512*5 f32, overwritten
    unsigned* counter = (unsigned*)(ws + NBLK_M * 5 * sizeof(float));

    hipMemsetAsync(counter, 0, sizeof(unsigned), stream);    // graph-safe node
    w2ner_fused<<<dim3(NBLK_M), 256, 0, stream>>>(x, span, seqlen, Wm, bias,
                                                  out, accum, counter);
}

// Round 17
// 27.832 us; speedup vs baseline: 2.3928x; 2.3928x over previous
//
#include <hip/hip_runtime.h>
#include <math.h>

#define NB 4
#define NN 512
#define ND 128
#define NC 10
#define NT 32                // 16-wide tiles per side
#define NBLK_M (NB*NT*8)     // 1024 blocks: (b, Tj, ig); ig = group of 4 i-tiles

typedef short    bf16x8 __attribute__((ext_vector_type(8)));
typedef unsigned u32x4  __attribute__((ext_vector_type(4)));
typedef float    f32x4  __attribute__((ext_vector_type(4)));

// pack two f32 into two truncated bf16 (low short = a, high short = b)
static __device__ __forceinline__ unsigned pack_trunc(float a, float b) {
    unsigned ua = __builtin_bit_cast(unsigned, a);
    unsigned ub = __builtin_bit_cast(unsigned, b);
    return (ua >> 16) | (ub & 0xFFFF0000u);
}

// K-split fused kernel: wave-pairs share 2 i-tiles; wave h computes K-half h
// (g in {2h, 2h+1}) for BOTH tiles, partials meet in LDS, each wave finalizes
// ONE tile. Total work identical to r11; grid doubles (1024 blocks -> 4
// blocks/CU, 4 waves/SIMD) and every per-wave serial chain halves.
// Frag semantics (r9-r16 verified, absmax 256 vs thr 17694):
//   A-frag (g): lane l holds x[row = Ti*16 + (l&15)][d = 32g + 8*(l>>4) + e]
//   B-frag (c,g): lane l holds y_c[col = Tj*16 + (l&15)][same d-enumeration]
//   C/D: col = lane&15, row = (lane>>4)*4 + reg
__global__ __launch_bounds__(256) void w2ner_fused(
    const float* __restrict__ x, const int* __restrict__ span,
    const int* __restrict__ seqlen, const float* __restrict__ Wm,
    const float* __restrict__ bias, float* __restrict__ out,
    float* __restrict__ accum)
{
    __shared__ f32x4 sEx[NC][2][64];   // 20 KB exchange: [class][pair][lane]
    __shared__ float sRed[4 * 5];

    const int tid = threadIdx.x;
    const int blk = blockIdx.x;
    const int b   = blk >> 8;
    const int rem = blk & 255;
    const int Tj  = rem >> 3;
    const int ig  = rem & 7;
    const int wv = tid >> 6, l = tid & 63;
    const int pair = wv >> 1, h = wv & 1;     // h = K-half
    const int jl = l & 15, kg = l >> 4;
    const int Ti0 = ig * 4 + pair * 2;        // pair's first i-tile
    const int Tf  = Ti0 + h;                  // tile this wave finalizes
    const int j  = Tj * 16 + jl;
    const int sl = seqlen[b];
    const float* xb = x + (size_t)b * NN * ND;
    const size_t sb = (size_t)b * NN * NN;

    // span prefetch for the finalized tile only (4 loads, hides under MFMA)
    const int ibf = Tf * 16 + kg * 4;
    int sp[4];
    #pragma unroll
    for (int r = 0; r < 4; ++r)
        sp[r] = span[sb + (size_t)(ibf + r) * NN + j];

    // bias folded into h=0's accumulator init (added exactly once per logit)
    f32x4 acc[2][NC];
    #pragma unroll
    for (int c = 0; c < NC; ++c) {
        const float bc = (h == 0) ? bias[c] : 0.f;
        acc[0][c] = (f32x4){bc, bc, bc, bc};
        acc[1][c] = (f32x4){bc, bc, bc, bc};
    }

    #pragma unroll
    for (int gi = 0; gi < 2; ++gi) {
        const int g  = 2 * h + gi;
        const int d0 = 32 * g + 8 * kg;

        // A fragments (both i-tiles): exact hi/lo split (truncation)
        bf16x8 ah[2], al[2];
        #pragma unroll
        for (int m = 0; m < 2; ++m) {
            const int irow = (Ti0 + m) * 16 + jl;
            float xiv[8];
            *(float4*)&xiv[0] = *(const float4*)(xb + (size_t)irow * ND + d0);
            *(float4*)&xiv[4] = *(const float4*)(xb + (size_t)irow * ND + d0 + 4);
            u32x4 ahw, alw;
            #pragma unroll
            for (int e2 = 0; e2 < 4; ++e2) {
                const float a0 = xiv[2 * e2], a1 = xiv[2 * e2 + 1];
                const unsigned u0 = __builtin_bit_cast(unsigned, a0) & 0xFFFF0000u;
                const unsigned u1 = __builtin_bit_cast(unsigned, a1) & 0xFFFF0000u;
                ahw[e2] = (u0 >> 16) | u1;
                alw[e2] = pack_trunc(a0 - __builtin_bit_cast(float, u0),
                                     a1 - __builtin_bit_cast(float, u1));
            }
            ah[m] = __builtin_bit_cast(bf16x8, ahw);
            al[m] = __builtin_bit_cast(bf16x8, alw);
        }

        // B fragments (one per class): y = x_j * W, rounded once to bf16 (trunc)
        float xjv[8];
        *(float4*)&xjv[0] = *(const float4*)(xb + (size_t)j * ND + d0);
        *(float4*)&xjv[4] = *(const float4*)(xb + (size_t)j * ND + d0 + 4);
        u32x4 yw[NC];
        #pragma unroll
        for (int e2 = 0; e2 < 4; ++e2) {
            float wb[20];   // W rows d0+2e2, d0+2e2+1 (20 contiguous floats)
            const float4* wp = (const float4*)(Wm + (size_t)(d0 + 2 * e2) * NC);
            #pragma unroll
            for (int t5 = 0; t5 < 5; ++t5) *(float4*)&wb[4 * t5] = wp[t5];
            const float x0 = xjv[2 * e2], x1 = xjv[2 * e2 + 1];
            #pragma unroll
            for (int c = 0; c < NC; ++c)
                yw[c][e2] = pack_trunc(x0 * wb[c], x1 * wb[10 + c]);
        }

        #pragma unroll
        for (int c = 0; c < NC; ++c) {
            const bf16x8 bh = __builtin_bit_cast(bf16x8, yw[c]);
            #pragma unroll
            for (int m = 0; m < 2; ++m) {
                acc[m][c] = __builtin_amdgcn_mfma_f32_16x16x32_bf16(ah[m], bh, acc[m][c], 0, 0, 0);
                acc[m][c] = __builtin_amdgcn_mfma_f32_16x16x32_bf16(al[m], bh, acc[m][c], 0, 0, 0);
            }
        }
    }

    // ---- K-half exchange (2 barriers, per-pair LDS slice) ----
    if (h == 0) {                      // h0 ships its m=1 partial
        #pragma unroll
        for (int c = 0; c < NC; ++c) sEx[c][pair][l] = acc[1][c];
    }
    __syncthreads();
    if (h == 1) {                      // h1 completes m=1, ships its m=0 partial
        #pragma unroll
        for (int c = 0; c < NC; ++c) {
            const f32x4 t = sEx[c][pair][l];
            acc[1][c] += t;
            sEx[c][pair][l] = acc[0][c];
        }
    }
    __syncthreads();
    if (h == 0) {                      // h0 completes m=0
        #pragma unroll
        for (int c = 0; c < NC; ++c) acc[0][c] += sEx[c][pair][l];
    } else {                           // move finalized tile into slot 0
        #pragma unroll
        for (int c = 0; c < NC; ++c) acc[0][c] = acc[1][c];
    }

    // ---- fused softmax/focal epilogue for tile Tf (4 rows/lane) ----
    float lsum = 0.f, accn = 0.f, tpn = 0.f, tnn = 0.f, fpn = 0.f;
    #pragma unroll
    for (int r = 0; r < 4; ++r) {
        const int i = ibf + r;
        float L[NC];
        #pragma unroll
        for (int c = 0; c < NC; ++c) L[c] = acc[0][c][r];   // bias already in
        int am = 0; float mx = L[0];
        #pragma unroll
        for (int c = 1; c < NC; ++c) { if (L[c] > mx) { mx = L[c]; am = c; } }  // first-occurrence argmax
        float e[NC]; float s = 0.f;
        #pragma unroll
        for (int c = 0; c < NC; ++c) { e[c] = __expf(L[c] - mx); s += e[c]; }
        const int spv = sp[r];
        float lsp = L[0], esp = e[0];
        #pragma unroll
        for (int c = 1; c < NC; ++c) {
            lsp = (spv == c) ? L[c] : lsp;
            esp = (spv == c) ? e[c] : esp;
        }
        const float inv  = __builtin_amdgcn_rcpf(s);
        const float lp   = (lsp - mx) - __logf(s);
        const float prob = esp * inv;
        const float om   = 1.f - prob;
        const float lm   = -(om * om) * lp;
        const bool v = (i < sl) && (j < sl);
        const int pred = v ? am : 0;
        out[sb + (size_t)i * NN + j] = (float)pred;
        if (v) { lsum += lm; if (pred == spv) accn += 1.f; }
        if (spv > 0) { if (pred == spv) tpn += 1.f; else tnn += 1.f; }
        else if (pred > 0 && v) fpn += 1.f;
    }

    // block reduction -> per-block slot
    float vals[5] = { lsum, accn, tpn, tnn, fpn };
    #pragma unroll
    for (int k = 0; k < 5; ++k) {
        float vv = vals[k];
        for (int o = 32; o > 0; o >>= 1) vv += __shfl_down(vv, o);
        vals[k] = vv;
    }
    if (l == 0) {
        #pragma unroll
        for (int k = 0; k < 5; ++k) sRed[wv * 5 + k] = vals[k];
    }
    __syncthreads();
    if (tid < 5) {
        accum[(size_t)blk * 5 + tid] =
            sRed[tid] + sRed[5 + tid] + sRed[10 + tid] + sRed[15 + tid];
    }
}

__global__ __launch_bounds__(256) void w2ner_final(
    const int* __restrict__ seqlen, const float* __restrict__ accum,
    float* __restrict__ out)
{
    __shared__ float sP[4][5];
    const int tid = threadIdx.x;
    float part[5] = {0.f, 0.f, 0.f, 0.f, 0.f};
    for (int r = tid; r < NBLK_M; r += 256) {
        #pragma unroll
        for (int k = 0; k < 5; ++k) part[k] += accum[(size_t)r * 5 + k];
    }
    #pragma unroll
    for (int k = 0; k < 5; ++k) {
        float v = part[k];
        for (int o = 32; o > 0; o >>= 1) v += __shfl_down(v, o);
        part[k] = v;
    }
    const int wave = tid >> 6;
    const int lane = tid & 63;
    if (lane == 0) {
        #pragma unroll
        for (int k = 0; k < 5; ++k) sP[wave][k] = part[k];
    }
    __syncthreads();
    if (tid == 0) {
        float t[5];
        #pragma unroll
        for (int k = 0; k < 5; ++k) t[k] = sP[0][k] + sP[1][k] + sP[2][k] + sP[3][k];
        float s2 = 0.f;
        for (int k = 0; k < NB; ++k) { float s = (float)seqlen[k]; s2 += s * s; }
        const size_t base = (size_t)NB * NN * NN;
        out[base + 0] = t[2];          // tp
        out[base + 1] = t[3];          // tn
        out[base + 2] = t[4];          // fp
        out[base + 3] = t[0] / s2;     // loss
        out[base + 4] = t[1] / s2;     // accuracy
    }
}

extern "C" void kernel_launch(void* const* d_in, const int* in_sizes, int n_in,
                              void* d_out, int out_size, void* d_ws, size_t ws_size,
                              hipStream_t stream) {
    const float* x      = (const float*)d_in[0];
    const int*   span   = (const int*)d_in[1];
    const int*   seqlen = (const int*)d_in[2];
    const float* Wm     = (const float*)d_in[3];
    const float* bias   = (const float*)d_in[4];
    float* out   = (float*)d_out;
    float* accum = (float*)d_ws;   // 1024*5 f32, fully overwritten each launch

    w2ner_fused<<<dim3(NBLK_M), 256, 0, stream>>>(x, span, seqlen, Wm, bias, out, accum);
    w2ner_final<<<1, 256, 0, stream>>>(seqlen, accum, out);
}

// Round 18
// 24.182 us; speedup vs baseline: 2.7539x; 1.1509x over previous
//
#include <hip/hip_runtime.h>
#include <math.h>

#define NB 4
#define NN 512
#define ND 128
#define NC 10
#define NT 32                // 16-wide tiles per side
#define MREP 2               // i-tiles per wave
#define NBLK_M (NB*NT*4)     // 512 blocks: (b, Tj, q); q = octet of i-tiles

typedef short    bf16x8 __attribute__((ext_vector_type(8)));
typedef unsigned u32x4  __attribute__((ext_vector_type(4)));
typedef float    f32x4  __attribute__((ext_vector_type(4)));

// pack two f32 into two RNE bf16 (low short = a, high short = b).
// Plain __bf16 casts -> compiler fuses pairs into v_cvt_pk_bf16_f32.
static __device__ __forceinline__ unsigned pack_bf2(float a, float b) {
    unsigned short la = __builtin_bit_cast(unsigned short, (__bf16)a);
    unsigned short hb = __builtin_bit_cast(unsigned short, (__bf16)b);
    return (unsigned)la | ((unsigned)hb << 16);
}

// r11 shell (best measured: 23.7us), single-MFMA bf16 GEMM (the al*bh
// correction MFMA dropped: error was already y-trunc dominated at 2^-9;
// RNE rounding everywhere halves mean error vs r11's truncation).
// Frag semantics (r9-r17 verified):
//   A-frag (g): lane l holds x[row = Ti*16 + (l&15)][d = 32g + 8*(l>>4) + e]
//   B-frag (c,g): lane l holds y_c[col = Tj*16 + (l&15)][same d-enumeration]
//   C/D: col = lane&15, row = (lane>>4)*4 + reg
__global__ __launch_bounds__(256) void w2ner_fused(
    const float* __restrict__ x, const int* __restrict__ span,
    const int* __restrict__ seqlen, const float* __restrict__ Wm,
    const float* __restrict__ bias, float* __restrict__ out,
    float* __restrict__ accum)
{
    __shared__ float sRed[4 * 5];
    const int tid = threadIdx.x;
    const int blk = blockIdx.x;
    const int q  = blk & 3;
    const int Tj = (blk >> 2) & 31;
    const int b  = blk >> 7;
    const int wv = tid >> 6, l = tid & 63;
    const int jl = l & 15, kg = l >> 4;       // kg doubles as C/D row-group
    const int Ti0 = q * 8 + wv * MREP;
    const int j  = Tj * 16 + jl;
    const int sl = seqlen[b];
    const float* xb = x + (size_t)b * NN * ND;
    const size_t sb = (size_t)b * NN * NN;

    // span prefetch for the 8 pairs this lane owns (hides under the MFMA loop)
    int sp[MREP][4];
    #pragma unroll
    for (int m = 0; m < MREP; ++m) {
        const int ib = (Ti0 + m) * 16 + kg * 4;
        #pragma unroll
        for (int r = 0; r < 4; ++r)
            sp[m][r] = span[sb + (size_t)(ib + r) * NN + j];
    }

    // bias folded into accumulator init (MFMA C-in)
    f32x4 acc[MREP][NC];
    #pragma unroll
    for (int c = 0; c < NC; ++c) {
        const float bc = bias[c];
        #pragma unroll
        for (int m = 0; m < MREP; ++m) acc[m][c] = (f32x4){bc, bc, bc, bc};
    }

    #pragma unroll
    for (int g = 0; g < 4; ++g) {
        const int d0 = 32 * g + 8 * kg;

        // A fragments: RNE bf16 of x_i (no hi/lo split)
        bf16x8 ah[MREP];
        #pragma unroll
        for (int m = 0; m < MREP; ++m) {
            const int irow = (Ti0 + m) * 16 + jl;
            float xiv[8];
            *(float4*)&xiv[0] = *(const float4*)(xb + (size_t)irow * ND + d0);
            *(float4*)&xiv[4] = *(const float4*)(xb + (size_t)irow * ND + d0 + 4);
            u32x4 ahw;
            #pragma unroll
            for (int e2 = 0; e2 < 4; ++e2)
                ahw[e2] = pack_bf2(xiv[2 * e2], xiv[2 * e2 + 1]);
            ah[m] = __builtin_bit_cast(bf16x8, ahw);
        }

        // B fragments (one per class): y = x_j * W, RNE to bf16
        float xjv[8];
        *(float4*)&xjv[0] = *(const float4*)(xb + (size_t)j * ND + d0);
        *(float4*)&xjv[4] = *(const float4*)(xb + (size_t)j * ND + d0 + 4);
        u32x4 yw[NC];
        #pragma unroll
        for (int e2 = 0; e2 < 4; ++e2) {
            float wb[20];   // W rows d0+2e2, d0+2e2+1 (20 contiguous floats)
            const float4* wp = (const float4*)(Wm + (size_t)(d0 + 2 * e2) * NC);
            #pragma unroll
            for (int t5 = 0; t5 < 5; ++t5) *(float4*)&wb[4 * t5] = wp[t5];
            const float x0 = xjv[2 * e2], x1 = xjv[2 * e2 + 1];
            #pragma unroll
            for (int c = 0; c < NC; ++c)
                yw[c][e2] = pack_bf2(x0 * wb[c], x1 * wb[10 + c]);
        }

        // single MFMA per (c, m)
        #pragma unroll
        for (int c = 0; c < NC; ++c) {
            const bf16x8 bh = __builtin_bit_cast(bf16x8, yw[c]);
            #pragma unroll
            for (int m = 0; m < MREP; ++m)
                acc[m][c] = __builtin_amdgcn_mfma_f32_16x16x32_bf16(ah[m], bh, acc[m][c], 0, 0, 0);
        }
    }

    // fused softmax/focal epilogue (identical to r11)
    float lsum = 0.f, accn = 0.f, tpn = 0.f, tnn = 0.f, fpn = 0.f;
    #pragma unroll
    for (int m = 0; m < MREP; ++m) {
        const int ib = (Ti0 + m) * 16 + kg * 4;
        #pragma unroll
        for (int r = 0; r < 4; ++r) {
            const int i = ib + r;
            float L[NC];
            #pragma unroll
            for (int c = 0; c < NC; ++c) L[c] = acc[m][c][r];   // bias already in
            int am = 0; float mx = L[0];
            #pragma unroll
            for (int c = 1; c < NC; ++c) { if (L[c] > mx) { mx = L[c]; am = c; } }  // first-occurrence argmax
            float e[NC]; float s = 0.f;
            #pragma unroll
            for (int c = 0; c < NC; ++c) { e[c] = __expf(L[c] - mx); s += e[c]; }
            const int spv = sp[m][r];
            float lsp = L[0], esp = e[0];
            #pragma unroll
            for (int c = 1; c < NC; ++c) {
                lsp = (spv == c) ? L[c] : lsp;
                esp = (spv == c) ? e[c] : esp;
            }
            const float inv  = __builtin_amdgcn_rcpf(s);
            const float lp   = (lsp - mx) - __logf(s);
            const float prob = esp * inv;
            const float om   = 1.f - prob;
            const float lm   = -(om * om) * lp;
            const bool v = (i < sl) && (j < sl);
            const int pred = v ? am : 0;
            out[sb + (size_t)i * NN + j] = (float)pred;
            if (v) { lsum += lm; if (pred == spv) accn += 1.f; }
            if (spv > 0) { if (pred == spv) tpn += 1.f; else tnn += 1.f; }
            else if (pred > 0 && v) fpn += 1.f;
        }
    }

    // block reduction -> per-block slot, SoA layout accum[k][blk]
    float vals[5] = { lsum, accn, tpn, tnn, fpn };
    #pragma unroll
    for (int k = 0; k < 5; ++k) {
        float vv = vals[k];
        for (int o = 32; o > 0; o >>= 1) vv += __shfl_down(vv, o);
        vals[k] = vv;
    }
    if (l == 0) {
        #pragma unroll
        for (int k = 0; k < 5; ++k) sRed[wv * 5 + k] = vals[k];
    }
    __syncthreads();
    if (tid < 5) {
        accum[(size_t)tid * NBLK_M + blk] =
            sRed[tid] + sRed[5 + tid] + sRed[10 + tid] + sRed[15 + tid];
    }
}

__global__ __launch_bounds__(512) void w2ner_final(
    const int* __restrict__ seqlen, const float* __restrict__ accum,
    float* __restrict__ out)
{
    __shared__ float sP[8][5];
    const int tid = threadIdx.x;     // 512 threads == NBLK_M slots
    float part[5];
    #pragma unroll
    for (int k = 0; k < 5; ++k) part[k] = accum[(size_t)k * NBLK_M + tid];  // coalesced
    #pragma unroll
    for (int k = 0; k < 5; ++k) {
        float v = part[k];
        for (int o = 32; o > 0; o >>= 1) v += __shfl_down(v, o);
        part[k] = v;
    }
    const int wave = tid >> 6;
    const int lane = tid & 63;
    if (lane == 0) {
        #pragma unroll
        for (int k = 0; k < 5; ++k) sP[wave][k] = part[k];
    }
    __syncthreads();
    if (tid == 0) {
        float t[5];
        #pragma unroll
        for (int k = 0; k < 5; ++k) {
            float s = 0.f;
            #pragma unroll
            for (int w = 0; w < 8; ++w) s += sP[w][k];
            t[k] = s;
        }
        float s2 = 0.f;
        for (int k = 0; k < NB; ++k) { float s = (float)seqlen[k]; s2 += s * s; }
        const size_t base = (size_t)NB * NN * NN;
        out[base + 0] = t[2];          // tp
        out[base + 1] = t[3];          // tn
        out[base + 2] = t[4];          // fp
        out[base + 3] = t[0] / s2;     // loss
        out[base + 4] = t[1] / s2;     // accuracy
    }
}

extern "C" void kernel_launch(void* const* d_in, const int* in_sizes, int n_in,
                              void* d_out, int out_size, void* d_ws, size_t ws_size,
                              hipStream_t stream) {
    const float* x      = (const float*)d_in[0];
    const int*   span   = (const int*)d_in[1];
    const int*   seqlen = (const int*)d_in[2];
    const float* Wm     = (const float*)d_in[3];
    const float* bias   = (const float*)d_in[4];
    float* out   = (float*)d_out;
    float* accum = (float*)d_ws;   // 5*512 f32 SoA, fully overwritten each launch

    w2ner_fused<<<dim3(NBLK_M), 256, 0, stream>>>(x, span, seqlen, Wm, bias, out, accum);
    w2ner_final<<<1, 512, 0, stream>>>(seqlen, accum, out);
}